// Round 1
// baseline (258.317 us; speedup 1.0000x reference)
//
#include <hip/hip_runtime.h>

#define RW 8
#define LARGE_V 1e10f

// Extract the RW column indices of each check row of H (exactly RW ones per row
// by construction; pad with -1 defensively).
__global__ void extract_cols_kernel(const int* __restrict__ H, int* __restrict__ cols,
                                    int m, int n) {
    int i = blockIdx.x * blockDim.x + threadIdx.x;
    if (i >= m) return;
    const int* row = H + (size_t)i * n;
    int cnt = 0;
    for (int j = 0; j < n; ++j) {
        if (row[j] != 0) {
            if (cnt < RW) cols[i * RW + cnt] = j;
            ++cnt;
        }
    }
    for (; cnt < RW; ++cnt) cols[i * RW + cnt] = -1;
}

// Cast labels (int32) to float into the tail of d_out.
__global__ void labels_kernel(const int* __restrict__ labels, float* __restrict__ out,
                              int count) {
    int i = blockIdx.x * blockDim.x + threadIdx.x;
    if (i < count) out[i] = (float)labels[i];
}

// One block per batch element. soft vector lives in LDS across all iterations.
__global__ __launch_bounds__(256) void bp_kernel(const float* __restrict__ soft_in,
                                                 const int* __restrict__ cols,
                                                 const float* __restrict__ normalizer,
                                                 float* __restrict__ out,
                                                 int B, int n, int m, int niter) {
    extern __shared__ float smem[];
    float* soft = smem;           // [n]
    float* acc  = smem + n;       // [n]
    int*   cs   = (int*)(smem + 2 * n);  // [m*RW]

    const int b   = blockIdx.x;
    const int tid = threadIdx.x;
    const int nt  = blockDim.x;

    const float norm = log1pf(expf(normalizer[0]));  // softplus

    // Load soft row into LDS and emit stack slice 0 (= soft_input).
    for (int j = tid; j < n; j += nt) {
        float v = soft_in[(size_t)b * n + j];
        soft[j] = v;
        out[(size_t)b * n + j] = v;
    }
    for (int e = tid; e < m * RW; e += nt) cs[e] = cols[e];
    __syncthreads();

    for (int t = 0; t < niter; ++t) {
        for (int j = tid; j < n; j += nt) acc[j] = 0.0f;
        __syncthreads();

        for (int i = tid; i < m; i += nt) {
            int   c[RW];
            float v[RW];
            float ps  = 1.0f;          // product of signs (sign(0)=0 semantics)
            float mn1 = LARGE_V, mn2 = LARGE_V;
            #pragma unroll
            for (int k = 0; k < RW; ++k) {
                int cc = cs[i * RW + k];
                c[k] = cc;
                float vv = (cc >= 0) ? soft[cc] : 0.0f;
                v[k] = vv;
                if (cc >= 0) {
                    float s = (vv > 0.0f) ? 1.0f : ((vv < 0.0f) ? -1.0f : 0.0f);
                    ps *= s;
                    float a = fabsf(vv);
                    float p = (a == 0.0f) ? LARGE_V : a;   // reference: proc
                    if (p < mn1) { mn2 = mn1; mn1 = p; }
                    else if (p < mn2) { mn2 = p; }
                }
            }
            #pragma unroll
            for (int k = 0; k < RW; ++k) {
                int cc = c[k];
                if (cc < 0) continue;
                float vv = v[k];
                float s  = (vv > 0.0f) ? 1.0f : ((vv < 0.0f) ? -1.0f : 0.0f);
                float a  = fabsf(vv);
                float upd = (a == mn1) ? mn2 : mn1;        // reference: where(avc==smallest,...)
                float msg = norm * upd * (ps * s);          // extrinsic sign = prod*own
                atomicAdd(&acc[cc], msg);
            }
        }
        __syncthreads();

        float* slice = out + (size_t)(t + 1) * B * n + (size_t)b * n;
        for (int j = tid; j < n; j += nt) {
            float v = soft[j] + acc[j];
            soft[j] = v;
            slice[j] = v;
        }
        __syncthreads();
    }
}

extern "C" void kernel_launch(void* const* d_in, const int* in_sizes, int n_in,
                              void* d_out, int out_size, void* d_ws, size_t ws_size,
                              hipStream_t stream) {
    const float* soft_in    = (const float*)d_in[0];
    const int*   labels     = (const int*)d_in[1];
    const int*   H          = (const int*)d_in[2];
    const float* normalizer = (const float*)d_in[3];

    const int n = 1024;
    const int B = in_sizes[0] / n;          // 128
    const int m = in_sizes[2] / n;          // 512
    const int niter = out_size / (B * n) - 2;  // stack has niter+1 slices + labels

    int* cols = (int*)d_ws;  // m*RW ints = 16 KB

    extract_cols_kernel<<<(m + 255) / 256, 256, 0, stream>>>(H, cols, m, n);

    const int lab = B * n;
    float* out_labels = (float*)d_out + (size_t)(niter + 1) * B * n;
    labels_kernel<<<(lab + 255) / 256, 256, 0, stream>>>(labels, out_labels, lab);

    const size_t lds_bytes = (size_t)(2 * n) * sizeof(float) + (size_t)(m * RW) * sizeof(int);
    bp_kernel<<<B, 256, lds_bytes, stream>>>(soft_in, cols, normalizer, (float*)d_out,
                                             B, n, m, niter);
}

// Round 2
// 77.640 us; speedup vs baseline: 3.3271x; 3.3271x over previous
//
#include <hip/hip_runtime.h>

#define RW 8
#define LARGE_V 1e10f

// One wave per row. Lane l loads columns [l*16, l*16+16) as 4x int4 (coalesced),
// then a wave-wide exclusive prefix-sum assigns each nonzero its rank so the
// output column list is deterministic and ascending.
__global__ __launch_bounds__(64) void extract_cols_kernel(const int* __restrict__ H,
                                                          int* __restrict__ cols,
                                                          int m, int n) {
    const int i    = blockIdx.x;          // row
    const int lane = threadIdx.x;         // 0..63
    if (i >= m) return;

    const int per = 16;                   // n=1024 / 64 lanes
    const int4* rp = (const int4*)(H + (size_t)i * n + lane * per);

    int v[16];
    #pragma unroll
    for (int q = 0; q < 4; ++q) {
        int4 x = rp[q];
        v[q * 4 + 0] = x.x; v[q * 4 + 1] = x.y;
        v[q * 4 + 2] = x.z; v[q * 4 + 3] = x.w;
    }
    int cnt = 0;
    #pragma unroll
    for (int t = 0; t < 16; ++t) cnt += (v[t] != 0);

    // exclusive prefix over 64 lanes
    int pre = cnt;
    #pragma unroll
    for (int d = 1; d < 64; d <<= 1) {
        int o = __shfl_up(pre, d);
        if (lane >= d) pre += o;
    }
    pre -= cnt;

    int k = 0;
    #pragma unroll
    for (int t = 0; t < 16; ++t) {
        if (v[t] != 0) {
            if (pre + k < RW) cols[i * RW + pre + k] = lane * per + t;
            ++k;
        }
    }
    // defensive padding if row had fewer than RW ones (shouldn't happen)
    if (lane == 63) {
        int total = pre + cnt;
        for (int p = total; p < RW; ++p) cols[i * RW + p] = -1;
    }
}

// Cast labels (int32) to float into the tail of d_out.
__global__ void labels_kernel(const int* __restrict__ labels, float* __restrict__ out,
                              int count) {
    int i = blockIdx.x * blockDim.x + threadIdx.x;
    if (i < count) out[i] = (float)labels[i];
}

// One block per batch element; 512 threads; each thread owns one check row
// (cols in registers). soft + acc live in LDS across all iterations.
__global__ __launch_bounds__(512) void bp_kernel(const float* __restrict__ soft_in,
                                                 const int* __restrict__ cols,
                                                 const float* __restrict__ normalizer,
                                                 float* __restrict__ out,
                                                 int B, int n, int m, int niter) {
    __shared__ float soft[1024];
    __shared__ float acc[1024];

    const int b   = blockIdx.x;
    const int tid = threadIdx.x;
    const int nt  = blockDim.x;   // 512

    const float norm = log1pf(expf(normalizer[0]));  // softplus

    // my check row's column indices (one check per thread), coalesced int4 x2
    int c[RW];
    if (tid < m) {
        const int4* cp = (const int4*)(cols + tid * RW);
        int4 a0 = cp[0], a1 = cp[1];
        c[0] = a0.x; c[1] = a0.y; c[2] = a0.z; c[3] = a0.w;
        c[4] = a1.x; c[5] = a1.y; c[6] = a1.z; c[7] = a1.w;
    } else {
        #pragma unroll
        for (int k = 0; k < RW; ++k) c[k] = -1;
    }

    // Load soft row into LDS, emit stack slice 0, zero acc.
    for (int j = tid; j < n; j += nt) {
        float v = soft_in[(size_t)b * n + j];
        soft[j] = v;
        acc[j]  = 0.0f;
        out[(size_t)b * n + j] = v;
    }
    __syncthreads();

    for (int t = 0; t < niter; ++t) {
        // --- check-node phase: one check per thread ---
        if (tid < m) {
            float v[RW];
            float ps  = 1.0f;                 // product of signs (sign(0)=0)
            float mn1 = LARGE_V, mn2 = LARGE_V;
            #pragma unroll
            for (int k = 0; k < RW; ++k) {
                int cc = c[k];
                float vv = (cc >= 0) ? soft[cc] : 0.0f;
                v[k] = vv;
                if (cc >= 0) {
                    float s = (vv > 0.0f) ? 1.0f : ((vv < 0.0f) ? -1.0f : 0.0f);
                    ps *= s;
                    float a = fabsf(vv);
                    float p = (a == 0.0f) ? LARGE_V : a;    // reference: proc
                    if (p < mn1) { mn2 = mn1; mn1 = p; }
                    else if (p < mn2) { mn2 = p; }
                }
            }
            #pragma unroll
            for (int k = 0; k < RW; ++k) {
                int cc = c[k];
                if (cc < 0) continue;
                float vv = v[k];
                float s  = (vv > 0.0f) ? 1.0f : ((vv < 0.0f) ? -1.0f : 0.0f);
                float a  = fabsf(vv);
                float upd = (a == mn1) ? mn2 : mn1;         // top-2 min-sum
                atomicAdd(&acc[cc], norm * upd * (ps * s));
            }
        }
        __syncthreads();

        // --- variable-node phase: marginalize, emit slice, re-zero acc ---
        float* slice = out + (size_t)(t + 1) * B * n + (size_t)b * n;
        for (int j = tid; j < n; j += nt) {
            float v = soft[j] + acc[j];
            soft[j] = v;
            acc[j]  = 0.0f;
            slice[j] = v;
        }
        __syncthreads();
    }
}

extern "C" void kernel_launch(void* const* d_in, const int* in_sizes, int n_in,
                              void* d_out, int out_size, void* d_ws, size_t ws_size,
                              hipStream_t stream) {
    const float* soft_in    = (const float*)d_in[0];
    const int*   labels     = (const int*)d_in[1];
    const int*   H          = (const int*)d_in[2];
    const float* normalizer = (const float*)d_in[3];

    const int n = 1024;
    const int B = in_sizes[0] / n;             // 128
    const int m = in_sizes[2] / n;             // 512
    const int niter = out_size / (B * n) - 2;  // 10

    int* cols = (int*)d_ws;  // m*RW ints = 16 KB

    extract_cols_kernel<<<m, 64, 0, stream>>>(H, cols, m, n);

    const int lab = B * n;
    float* out_labels = (float*)d_out + (size_t)(niter + 1) * B * n;
    labels_kernel<<<(lab + 255) / 256, 256, 0, stream>>>(labels, out_labels, lab);

    bp_kernel<<<B, 512, 0, stream>>>(soft_in, cols, normalizer, (float*)d_out,
                                     B, n, m, niter);
}

// Round 3
// 28.750 us; speedup vs baseline: 8.9850x; 2.7006x over previous
//
#include <hip/hip_runtime.h>

#define RW 8
#define LARGE_V 1e10f
#define MAXI 10            // max supported iterations (stack sized MAXI+1)
#define NV 1024            // n
#define SCALE 1048576.0f   // 2^20 fixed-point scale for LDS accumulation
#define INV_SCALE (1.0f / 1048576.0f)

// Fused setup: blocks [0,m) extract the RW column indices per check row
// (one wave per row, coalesced int4 loads + wave prefix-sum for deterministic
// ascending order); blocks [m, m+labBlocks) cast labels int32 -> float32.
__global__ __launch_bounds__(64) void setup_kernel(const int* __restrict__ H,
                                                   int* __restrict__ cols,
                                                   int m, int n,
                                                   const int* __restrict__ labels,
                                                   float* __restrict__ out_labels,
                                                   int lab_count) {
    const int blk  = blockIdx.x;
    const int lane = threadIdx.x;  // 0..63

    if (blk < m) {
        const int per = 16;  // n=1024 / 64 lanes
        const int4* rp = (const int4*)(H + (size_t)blk * n + lane * per);
        int v[16];
        #pragma unroll
        for (int q = 0; q < 4; ++q) {
            int4 x = rp[q];
            v[q * 4 + 0] = x.x; v[q * 4 + 1] = x.y;
            v[q * 4 + 2] = x.z; v[q * 4 + 3] = x.w;
        }
        int cnt = 0;
        #pragma unroll
        for (int t = 0; t < 16; ++t) cnt += (v[t] != 0);
        // exclusive prefix over 64 lanes
        int pre = cnt;
        #pragma unroll
        for (int d = 1; d < 64; d <<= 1) {
            int o = __shfl_up(pre, d);
            if (lane >= d) pre += o;
        }
        pre -= cnt;
        int k = 0;
        #pragma unroll
        for (int t = 0; t < 16; ++t) {
            if (v[t] != 0) {
                if (pre + k < RW) cols[blk * RW + pre + k] = lane * per + t;
                ++k;
            }
        }
        if (lane == 63) {
            int total = pre + cnt;
            for (int p = total; p < RW; ++p) cols[blk * RW + p] = -1;
        }
    } else {
        // labels chunk: 1024 elements per block, coalesced int4 -> float4
        const int chunk = blk - m;
        const int base  = chunk * 1024;
        #pragma unroll
        for (int q = 0; q < 4; ++q) {
            int idx = base + q * 256 + lane * 4;
            if (idx + 3 < lab_count) {
                int4 x = *(const int4*)(labels + idx);
                float4 f;
                f.x = (float)x.x; f.y = (float)x.y;
                f.z = (float)x.z; f.w = (float)x.w;
                *(float4*)(out_labels + idx) = f;
            } else {
                for (int t = 0; t < 4; ++t)
                    if (idx + t < lab_count) out_labels[idx + t] = (float)labels[idx + t];
            }
        }
    }
}

// One block per batch element; 512 threads; thread tid owns check row tid
// (cols in registers). Full output stack kept in LDS; int fixed-point LDS
// accumulation (native ds_add_u32, no CAS loop, deterministic).
__global__ __launch_bounds__(512) void bp_kernel(const float* __restrict__ soft_in,
                                                 const int* __restrict__ cols,
                                                 const float* __restrict__ normalizer,
                                                 float* __restrict__ out,
                                                 int B, int n, int m, int niter) {
    __shared__ float stack[MAXI + 1][NV];
    __shared__ int   iacc[NV];

    const int b   = blockIdx.x;
    const int tid = threadIdx.x;
    const int nt  = blockDim.x;  // 512

    const float norm = log1pf(expf(normalizer[0]));  // softplus

    // my check row's columns (m == blockDim == 512), coalesced int4 x2
    int c[RW];
    if (tid < m) {
        const int4* cp = (const int4*)(cols + tid * RW);
        int4 a0 = cp[0], a1 = cp[1];
        c[0] = a0.x; c[1] = a0.y; c[2] = a0.z; c[3] = a0.w;
        c[4] = a1.x; c[5] = a1.y; c[6] = a1.z; c[7] = a1.w;
    } else {
        #pragma unroll
        for (int k = 0; k < RW; ++k) c[k] = -1;
    }

    for (int j = tid; j < n; j += nt) {
        stack[0][j] = soft_in[(size_t)b * n + j];
        iacc[j] = 0;
    }
    __syncthreads();

    if (niter > MAXI) niter = MAXI;

    for (int t = 0; t < niter; ++t) {
        const float* cur = stack[t];

        // --- check-node phase ---
        {
            float v[RW];
            float ps  = 1.0f;               // product of signs (sign(0)=0)
            float mn1 = LARGE_V, mn2 = LARGE_V;
            #pragma unroll
            for (int k = 0; k < RW; ++k) {
                int cc = c[k];
                float vv = (cc >= 0) ? cur[cc] : 0.0f;
                v[k] = vv;
                if (cc >= 0) {
                    float s = (vv > 0.0f) ? 1.0f : ((vv < 0.0f) ? -1.0f : 0.0f);
                    ps *= s;
                    float a = fabsf(vv);
                    float p = (a == 0.0f) ? LARGE_V : a;   // reference: proc
                    if (p < mn1) { mn2 = mn1; mn1 = p; }
                    else if (p < mn2) { mn2 = p; }
                }
            }
            #pragma unroll
            for (int k = 0; k < RW; ++k) {
                int cc = c[k];
                if (cc < 0) continue;
                float vv = v[k];
                float s  = (vv > 0.0f) ? 1.0f : ((vv < 0.0f) ? -1.0f : 0.0f);
                float a  = fabsf(vv);
                float upd = (a == mn1) ? mn2 : mn1;        // top-2 min-sum
                float msg = norm * upd * (ps * s);
                atomicAdd(&iacc[cc], __float2int_rn(msg * SCALE));  // ds_add_u32
            }
        }
        __syncthreads();

        // --- variable-node phase: 2 vars per thread, re-zero iacc ---
        {
            const int j0 = tid * 2;
            float2 sp = *(const float2*)&stack[t][j0];
            int2   ia = *(const int2*)&iacc[j0];
            float2 nv;
            nv.x = sp.x + (float)ia.x * INV_SCALE;
            nv.y = sp.y + (float)ia.y * INV_SCALE;
            *(float2*)&stack[t + 1][j0] = nv;
            int2 z; z.x = 0; z.y = 0;
            *(int2*)&iacc[j0] = z;
        }
        __syncthreads();
    }

    // --- coalesced writeout of all (niter+1) slices ---
    const int nq = n / 4;  // float4s per slice
    for (int idx = tid; idx < (niter + 1) * nq; idx += nt) {
        int slice = idx / nq;
        int pos   = idx - slice * nq;
        float4 val = *(const float4*)&stack[slice][pos * 4];
        *(float4*)(out + ((size_t)slice * B + b) * n + (size_t)pos * 4) = val;
    }
}

extern "C" void kernel_launch(void* const* d_in, const int* in_sizes, int n_in,
                              void* d_out, int out_size, void* d_ws, size_t ws_size,
                              hipStream_t stream) {
    const float* soft_in    = (const float*)d_in[0];
    const int*   labels     = (const int*)d_in[1];
    const int*   H          = (const int*)d_in[2];
    const float* normalizer = (const float*)d_in[3];

    const int n = 1024;
    const int B = in_sizes[0] / n;             // 128
    const int m = in_sizes[2] / n;             // 512
    const int niter = out_size / (B * n) - 2;  // 10

    int* cols = (int*)d_ws;  // m*RW ints = 16 KB

    const int lab = B * n;   // label count
    float* out_labels = (float*)d_out + (size_t)(niter + 1) * B * n;
    const int lab_blocks = (lab + 1023) / 1024;

    setup_kernel<<<m + lab_blocks, 64, 0, stream>>>(H, cols, m, n,
                                                    labels, out_labels, lab);

    bp_kernel<<<B, 512, 0, stream>>>(soft_in, cols, normalizer, (float*)d_out,
                                     B, n, m, niter);
}